// Round 2
// baseline (476.929 us; speedup 1.0000x reference)
//
#include <hip/hip_runtime.h>
#include <hip/hip_bf16.h>

typedef __attribute__((ext_vector_type(8))) __bf16 bf16x8;
typedef __attribute__((ext_vector_type(4))) __bf16 bf16x4;
typedef __attribute__((ext_vector_type(4))) float f32x4;

constexpr int M  = 16384;
constexpr int K  = 512;   // both GEMM reduction dims (DIN = H = 512)
constexpr int BK = 32;
constexpr int R  = 64;    // rows per block

__device__ __forceinline__ void async_copy16(const void* gsrc, void* ldst) {
  __builtin_amdgcn_global_load_lds(
      (const __attribute__((address_space(1))) unsigned int*)(gsrc),
      (__attribute__((address_space(3))) unsigned int*)(ldst),
      16, 0, 0);
}

__device__ __forceinline__ float frcp(float x) { return __builtin_amdgcn_rcpf(x); }
__device__ __forceinline__ float ftanh(float x) {
  return 1.0f - 2.0f * frcp(1.0f + __expf(2.0f * x));
}
__device__ __forceinline__ float fsigm(float x) { return frcp(1.0f + __expf(-x)); }

// ---------------------------------------------------------------------------
// Fully fused LSTM-cell kernel, spill-free revision of R1.
// One block = 64 rows, 512 threads (8 waves, each owns a 64-col slice of
// N=512). Nets processed in order j=0:i2, j=1:f2, j=2:z.
//   layer1: h1 = hx(fp32->bf16 reg-staged) @ W1[j]^T -> tanh -> a1 (LDS,
//           XOR-swizzled so layer2 A-frag ds_read_b128 is conflict-free)
//   layer2: h2 = a1 @ W2[j]^T  (A-operand straight from LDS, no staging)
//   j=0/1 epilogue: gate = sigmoid(tanh(.)) -> bf16 -> gates ws (L2-hot,
//           re-read by the same thread in j=2; 32 intervening barriers with
//           implicit vmcnt(0) order the RAW).
//   j=2 epilogue: z = tanh(gate), out = f2*cx2 + i2*z (fp32, direct).
// R1 POST-MORTEM: register stash of i2/f2 across the j-loop pushed live set
// to ~185 VGPR; backend targeted 4 waves/EU (=128 VGPR) and spilled ~2.7KB/
// thread into the K-loops (WRITE_SIZE 360MB, MfmaUtil 8%). Occupancy is
// LDS-bound at 2 waves/EU anyway, so the spill bought nothing. Fixes:
// (a) no cross-net register stash (gates roundtrip via ws instead),
// (b) amdgpu_waves_per_eu(2,2) pins the allocator to the 256-VGPR budget.
// LDS: Wbuf 2x[512][32] (64KB) | Abuf 2x[64][32] (8KB) | a1 [64][512] (64KB)
//    = 136 KB -> 1 block/CU, grid 256 = exactly 1 block per CU.
// Buffer-reuse safety: every phase's last K-step (s=15, odd) reads Wbuf1;
// each prologue writes Wbuf0, and all s=14 Wbuf0 reads retire before the
// s=15 barrier that precedes any prologue -> no race without extra barriers.
// NOTE: never runtime-index acc[] (scratch spill) - all loops unrolled.
// ---------------------------------------------------------------------------
__global__ __attribute__((amdgpu_waves_per_eu(2, 2)))
__launch_bounds__(512) void fused_kernel(
    const float* __restrict__ hx,    // [M][512] fp32
    const __bf16* __restrict__ W1b,  // [3][512][512] bf16 (N,K) row-major
    const __bf16* __restrict__ W2b,  // [3][512][512] bf16
    const float* __restrict__ b1,    // [7][512] fp32 (use row 2j+1)
    const float* __restrict__ b2,    // [7][512] fp32
    const float* __restrict__ cx2,   // [M][512] fp32
    __bf16* __restrict__ gates,      // ws [2][M][512] bf16 (i2, f2)
    float* __restrict__ out)         // [M][512] fp32
{
  __shared__ __align__(16) __bf16 smem[69632];   // 136 KB
  __bf16* const a1 = smem + 36864;
  constexpr size_t NH = (size_t)M * 512;

  const int mbase = blockIdx.x * R;
  const int tid = threadIdx.x, wid = tid >> 6, lane = tid & 63;
  const int wn   = wid * 64;                       // wave's col slice
  const int srow = wid * 16 + (lane >> 2);         // gload_lds row mapping
  const int scol = ((lane & 3) ^ ((lane >> 3) & 3)) * 8;  // swizzled src chunk
  const int fr = lane & 15, kc = lane >> 4;
  const int sw = (fr >> 1) & 3, rowq = kc * 4;

  // A (hx) reg-staging mapping: thread -> (row, 4-float chunk); dest chunk is
  // pre-swizzled so frag reads use the same (kc^sw) un-swizzle as W tiles.
  const int ar = tid >> 3, ac = tid & 7;
  const int adst = ar * 32 + (((ac >> 1) ^ ((ar >> 1) & 3)) * 8) + (ac & 1) * 4;
  const float* hxrow = hx + (size_t)(mbase + ar) * K + ac * 4;

  auto stageW = [&](int p, int k0, const __bf16* Wj) {
#pragma unroll
    for (int r = 0; r < 4; ++r)
      async_copy16(Wj + (size_t)(r * 128 + srow) * K + (k0 + scol),
                   (void*)&smem[p * 16384 + (r * 128 + wid * 16) * BK]);
  };

#pragma unroll 1
  for (int j = 0; j < 3; ++j) {
    const __bf16* WL1 = W1b + (size_t)j * 262144;
    const __bf16* WL2 = W2b + (size_t)j * 262144;

    // ---------------- layer 1 ----------------
    {
      f32x4 acc[4][4] = {};
      {
        f32x4 av = *(const f32x4*)(hxrow);   // issue before stageW: oldest vmem
        stageW(0, 0, WL1);
        *(bf16x4*)&smem[32768 + adst] = __builtin_convertvector(av, bf16x4);
      }
      int p = 0;
      for (int k0 = 0; k0 < K; k0 += BK) {
        __syncthreads();               // drains stage(p) issued last iter
        const bool pre = k0 + BK < K;
        f32x4 av;
        if (pre) {
          av = *(const f32x4*)(hxrow + k0 + BK);
          stageW(p ^ 1, k0 + BK, WL1);
        }
        bf16x8 af[4], bfr[4];
#pragma unroll
        for (int i = 0; i < 4; ++i) {
          af[i]  = *(const bf16x8*)&smem[32768 + p * 2048 +
                                         (i * 16 + fr) * BK + ((kc ^ sw) * 8)];
          bfr[i] = *(const bf16x8*)&smem[p * 16384 +
                                         (wn + i * 16 + fr) * BK + ((kc ^ sw) * 8)];
        }
#pragma unroll
        for (int mi = 0; mi < 4; ++mi)
#pragma unroll
          for (int ni = 0; ni < 4; ++ni)
            acc[mi][ni] = __builtin_amdgcn_mfma_f32_16x16x32_bf16(
                af[mi], bfr[ni], acc[mi][ni], 0, 0, 0);
        if (pre)   // next-iter A tile; published by next iteration's barrier
          *(bf16x4*)&smem[32768 + (p ^ 1) * 2048 + adst] =
              __builtin_convertvector(av, bf16x4);
        p ^= 1;
      }

      // epilogue: bias + tanh -> a1 (XOR swizzle keeps layer2 reads <=2-way)
      const float* b1j = b1 + (2 * j + 1) * 512 + wn;
      float bv[4];
#pragma unroll
      for (int ni = 0; ni < 4; ++ni) bv[ni] = b1j[ni * 16 + fr];
#pragma unroll
      for (int mi = 0; mi < 4; ++mi)
#pragma unroll
        for (int ni = 0; ni < 4; ++ni)
#pragma unroll
          for (int r = 0; r < 4; ++r) {
            const int row = mi * 16 + rowq + r;       // C layout: row=rowq+r
            const int col = wn + ni * 16 + fr;        //           col=fr
            a1[(row * 512 + col) ^ ((row & 7) << 3)] =
                (__bf16)ftanh(acc[mi][ni][r] + bv[ni]);
          }
    }

    // ---------------- layer 2 ----------------
    {
      stageW(0, 0, WL2);   // safe: last L1 step read Wbuf1, not Wbuf0
      f32x4 acc[4][4] = {};
      int p = 0;
      for (int k0 = 0; k0 < K; k0 += BK) {
        __syncthreads();   // publishes a1 writes (first iter) + drains stage
        if (k0 + BK < K) stageW(p ^ 1, k0 + BK, WL2);
        bf16x8 af[4], bfr[4];
#pragma unroll
        for (int i = 0; i < 4; ++i) {
          const int row = i * 16 + fr;
          af[i]  = *(const bf16x8*)&a1[(row * 512 + k0 + kc * 8) ^
                                       ((row & 7) << 3)];
          bfr[i] = *(const bf16x8*)&smem[p * 16384 +
                                         (wn + i * 16 + fr) * BK + ((kc ^ sw) * 8)];
        }
#pragma unroll
        for (int mi = 0; mi < 4; ++mi)
#pragma unroll
          for (int ni = 0; ni < 4; ++ni)
            acc[mi][ni] = __builtin_amdgcn_mfma_f32_16x16x32_bf16(
                af[mi], bfr[ni], acc[mi][ni], 0, 0, 0);
        p ^= 1;
      }

      const float* b2j = b2 + (2 * j + 1) * 512 + wn;
      float bv[4];
#pragma unroll
      for (int ni = 0; ni < 4; ++ni) bv[ni] = b2j[ni * 16 + fr];
      if (j < 2) {
        // i2 / f2: gate -> bf16 -> ws (same thread reads it back at j=2;
        // ordered by the 16+ intervening barriers' implicit vmcnt(0)).
        __bf16* gw = gates + (size_t)j * NH;
#pragma unroll
        for (int mi = 0; mi < 4; ++mi)
#pragma unroll
          for (int ni = 0; ni < 4; ++ni)
#pragma unroll
            for (int r = 0; r < 4; ++r) {
              const size_t idx = (size_t)(mbase + mi * 16 + rowq + r) * 512 +
                                 (wn + ni * 16 + fr);
              gw[idx] = (__bf16)fsigm(ftanh(acc[mi][ni][r] + bv[ni]));
            }
      } else {
        // z net: z = tanh(sigmoid(tanh(.))), then cy2 = f2*cx2 + i2*z
#pragma unroll
        for (int mi = 0; mi < 4; ++mi)
#pragma unroll
          for (int ni = 0; ni < 4; ++ni)
#pragma unroll
            for (int r = 0; r < 4; ++r) {
              const __bf16 zb =
                  (__bf16)ftanh(fsigm(ftanh(acc[mi][ni][r] + bv[ni])));
              const size_t idx = (size_t)(mbase + mi * 16 + rowq + r) * 512 +
                                 (wn + ni * 16 + fr);
              out[idx] = (float)gates[NH + idx] * cx2[idx] +
                         (float)gates[idx] * (float)zb;
            }
      }
    }
  }
}

// pick rows 2y+1 of W1/W2 ([7][512][512] fp32) -> [3][512][512] bf16 each
__global__ __launch_bounds__(256) void cvt_w6(const float* __restrict__ W1,
                                              const float* __restrict__ W2,
                                              __bf16* __restrict__ dst) {
  const int y = blockIdx.y;  // 0..2 -> W1 nets, 3..5 -> W2 nets
  const float* src = (y < 3) ? W1 + (size_t)(2 * y + 1) * 262144
                             : W2 + (size_t)(2 * (y - 3) + 1) * 262144;
  __bf16* d = dst + (size_t)y * 262144;
  const size_t i = ((size_t)blockIdx.x * 256 + threadIdx.x) * 4;
  f32x4 v = *(const f32x4*)&src[i];
  *(bf16x4*)&d[i] = __builtin_convertvector(v, bf16x4);
}

extern "C" void kernel_launch(void* const* d_in, const int* in_sizes, int n_in,
                              void* d_out, int out_size, void* d_ws, size_t ws_size,
                              hipStream_t stream) {
  const float* hx  = (const float*)d_in[0];
  // d_in[1] = cx1 (dead: cy1 is never returned)
  const float* cx2 = (const float*)d_in[2];
  const float* W1  = (const float*)d_in[3];
  const float* b1  = (const float*)d_in[4];
  const float* W2  = (const float*)d_in[5];
  const float* b2  = (const float*)d_in[6];

  // ws: W1b @0 (1.5 MB) | W2b @1.5MB | gates @3MB (32 MB) -> ~35 MB total
  __bf16* W1b   = (__bf16*)d_ws;
  __bf16* W2b   = W1b + 3 * 262144;
  __bf16* gates = W2b + 3 * 262144;

  cvt_w6<<<dim3(256, 6), 256, 0, stream>>>(W1, W2, W1b);
  fused_kernel<<<256, 512, 0, stream>>>(hx, W1b, W2b, b1, b2, cx2, gates,
                                        (float*)d_out);
}

// Round 3
// 271.453 us; speedup vs baseline: 1.7570x; 1.7570x over previous
//
#include <hip/hip_runtime.h>
#include <hip/hip_bf16.h>

typedef __attribute__((ext_vector_type(8))) __bf16 bf16x8;
typedef __attribute__((ext_vector_type(4))) __bf16 bf16x4;
typedef __attribute__((ext_vector_type(4))) float f32x4;

constexpr int M = 16384;
constexpr int K = 512;
constexpr int BK = 32;

__device__ __forceinline__ void async_copy16(const void* gsrc, void* ldst) {
  __builtin_amdgcn_global_load_lds(
      (const __attribute__((address_space(1))) unsigned int*)(gsrc),
      (__attribute__((address_space(3))) unsigned int*)(ldst),
      16, 0, 0);
}

__device__ __forceinline__ float frcp(float x) { return __builtin_amdgcn_rcpf(x); }
__device__ __forceinline__ float ftanh(float x) {
  return 1.0f - 2.0f * frcp(1.0f + __expf(2.0f * x));
}
__device__ __forceinline__ float fsigm(float x) { return frcp(1.0f + __expf(-x)); }

// ---------------------------------------------------------------------------
// R3: revert to the R0-proven GEMM structure (256 thr, 128x128 tile, BK=32,
// 4 waves 2x2, 34 KB LDS -> 4 blocks/CU, ~90 VGPR, NO spill) and bank the
// fusion wins as launch-level changes only:
//   MODE 1: a1[j] = tanh(hx @ W1[j]^T + b1)       A = hx fp32, reg-staged cvt
//           (folds the old cvt_hx kernel into the GEMM A-path)
//   MODE 2: gates[j] = sigm(tanh(a1[j] @ W2[j]^T + b2))   j in {0:i2, 1:f2}
//   MODE 3: z = tanh(sigm(tanh(a1[2] @ W2[2]^T + b2)));
//           out = f2*cx2 + i2*z   (reads gates from the PRIOR dispatch --
//           stream-ordered, no race; folds the old final_kernel)
// R1/R2 POST-MORTEM (megafusion, 512thr/136KB LDS/1 block/CU): VGPR pinned
// at 128 with ~230MB scratch round-trip per dispatch, all pipes <8% busy;
// waves_per_eu didn't lift the budget. Abandoned: 1 block/CU has zero TLP
// to hide barrier drains even when spill-free.
// NOTE: never partially-unroll loops indexing acc[] (R2-era lesson: scratch).
// ---------------------------------------------------------------------------
template <int MODE>
__global__ __launch_bounds__(256) void gemm_kernel(
    const float* __restrict__ hx,      // MODE1 A source [M][512] fp32
    const __bf16* __restrict__ Ab,     // MODE2/3 A source planes [3][M][512]
    const __bf16* __restrict__ W,      // [3][512][512] bf16 (N,K) row-major
    const float* __restrict__ bias,    // [7][512] fp32
    __bf16* __restrict__ outb,         // MODE1: a1 base; MODE2: gates base
    const __bf16* __restrict__ gates,  // MODE3: [2][M][512] bf16 (i2, f2)
    const float* __restrict__ cx2,     // MODE3
    float* __restrict__ outf)          // MODE3: [M][512] fp32
{
  const int j = blockIdx.z;
  const int jj = (MODE == 3) ? 2 : j;         // net index
  const int mbase = blockIdx.x * 128;
  const int nbase = blockIdx.y * 128;
  constexpr size_t NH = (size_t)M * 512;

  const __bf16* Wj = W + (size_t)jj * 262144;
  const __bf16* Abj = (MODE >= 2) ? Ab + (size_t)jj * NH : nullptr;
  const int brow = 2 * jj + 1;                // i2=1, f2=3, z=5

  // dbuf: 2 x (As 4096 el + Bs 4096 el) = 16384 el (32 KB).
  // epilogue scratch (MODE 1/2): 128 x 136 el = 17408 el (34 KB).
  __shared__ __align__(16) __bf16 smem[17408];

  const int tid  = threadIdx.x;
  const int wid  = tid >> 6;
  const int lane = tid & 63;
  const int wm   = (wid >> 1) * 64;
  const int wn   = (wid & 1) * 64;
  const int srow = wid * 16 + (lane >> 2);
  const int scol = ((lane & 3) ^ ((lane >> 3) & 3)) * 8;  // swizzled src chunk
  const int fr   = lane & 15;
  const int kc   = lane >> 4;
  const int sw   = (fr >> 1) & 3;
  const int rowq = kc * 4;

  // MODE1 A reg-staging: 2 threads/row, each covers 2 chunks (16 floats).
  const int ar = tid >> 1;              // row 0..127
  const int cb = (tid & 1) * 2;         // first of 2 chunks (chunk = 8 els)
  const int asw = (ar >> 1) & 3;        // same row-swizzle as frag reads
  const float* hxrow =
      (MODE == 1) ? hx + (size_t)(mbase + ar) * K + cb * 8 : nullptr;

  auto stage = [&](int p, int k0) {
    __bf16* As = smem + p * 8192;
    __bf16* Bs = As + 4096;
#pragma unroll
    for (int r = 0; r < 2; ++r)
      async_copy16(Wj + (size_t)(nbase + r * 64 + srow) * K + (k0 + scol),
                   (void*)&Bs[(r * 64 + wid * 16) * BK]);
    if constexpr (MODE >= 2) {
#pragma unroll
      for (int r = 0; r < 2; ++r)
        async_copy16(Abj + (size_t)(mbase + r * 64 + srow) * K + (k0 + scol),
                     (void*)&As[(r * 64 + wid * 16) * BK]);
    } else {
      const float* hp = hxrow + k0;
      f32x4 v0 = *(const f32x4*)(hp);
      f32x4 v1 = *(const f32x4*)(hp + 4);
      f32x4 v2 = *(const f32x4*)(hp + 8);
      f32x4 v3 = *(const f32x4*)(hp + 12);
      __bf16* As_ = As + ar * 32;
      *(bf16x4*)&As_[(cb ^ asw) * 8]           = __builtin_convertvector(v0, bf16x4);
      *(bf16x4*)&As_[(cb ^ asw) * 8 + 4]       = __builtin_convertvector(v1, bf16x4);
      *(bf16x4*)&As_[((cb + 1) ^ asw) * 8]     = __builtin_convertvector(v2, bf16x4);
      *(bf16x4*)&As_[((cb + 1) ^ asw) * 8 + 4] = __builtin_convertvector(v3, bf16x4);
    }
  };

  f32x4 acc[4][4] = {};

  stage(0, 0);
  int p = 0;
  for (int k0 = 0; k0 < K; k0 += BK) {
    __syncthreads();  // drains stage(p) issued last iter (or prologue)
    if (k0 + BK < K) stage(p ^ 1, k0 + BK);  // in flight during MFMA below

    const __bf16* As = smem + p * 8192;
    const __bf16* Bs = As + 4096;
    bf16x8 af[4], bfr[4];
#pragma unroll
    for (int i = 0; i < 4; ++i) {
      af[i]  = *(const bf16x8*)&As[(wm + i * 16 + fr) * BK + ((kc ^ sw) * 8)];
      bfr[i] = *(const bf16x8*)&Bs[(wn + i * 16 + fr) * BK + ((kc ^ sw) * 8)];
    }
#pragma unroll
    for (int mi = 0; mi < 4; ++mi)
#pragma unroll
      for (int ni = 0; ni < 4; ++ni)
        acc[mi][ni] = __builtin_amdgcn_mfma_f32_16x16x32_bf16(
            af[mi], bfr[ni], acc[mi][ni], 0, 0, 0);
    p ^= 1;
  }

  // Epilogue. C/D layout: col=fr, row=rowq+r.
  float bv[4];
  const float* bj = bias + (size_t)brow * 512 + nbase + wn;
#pragma unroll
  for (int ni = 0; ni < 4; ++ni) bv[ni] = bj[ni * 16 + fr];

  if constexpr (MODE <= 2) {
    __syncthreads();  // all frag reads done; smem reusable as C scratch
#pragma unroll
    for (int mi = 0; mi < 4; ++mi)
#pragma unroll
      for (int ni = 0; ni < 4; ++ni)
#pragma unroll
        for (int r = 0; r < 4; ++r) {
          float v = acc[mi][ni][r] + bv[ni];
          float res = (MODE == 1) ? ftanh(v) : fsigm(ftanh(v));
          smem[(wm + mi * 16 + rowq + r) * 136 + (wn + ni * 16 + fr)] =
              (__bf16)res;
        }
    __syncthreads();
#pragma unroll
    for (int it = 0; it < 8; ++it) {
      const int s = it * 256 + tid;   // 0..2047
      const int row = s >> 4, ch = s & 15;
      bf16x8 v = *(const bf16x8*)&smem[row * 136 + ch * 8];
      *(bf16x8*)&outb[(size_t)j * NH + (size_t)(mbase + row) * 512 +
                      (nbase + ch * 8)] = v;
    }
  } else {
    // z + combine: out = f2*cx2 + i2*z  (i2/f2 from prior dispatch; bf16
    // rounding of z matches the old gates-roundtrip numerics exactly)
#pragma unroll
    for (int mi = 0; mi < 4; ++mi)
#pragma unroll
      for (int ni = 0; ni < 4; ++ni)
#pragma unroll
        for (int r = 0; r < 4; ++r) {
          float v = acc[mi][ni][r] + bv[ni];
          const __bf16 zb = (__bf16)ftanh(fsigm(ftanh(v)));
          const size_t idx =
              (size_t)(mbase + wm + mi * 16 + rowq + r) * 512 +
              (nbase + wn + ni * 16 + fr);
          outf[idx] = (float)gates[NH + idx] * cx2[idx] +
                      (float)gates[idx] * (float)zb;
        }
  }
}

// pick rows 2y+1 of W1/W2 ([7][512][512] fp32) -> [3][512][512] bf16 each
__global__ __launch_bounds__(256) void cvt_w6(const float* __restrict__ W1,
                                              const float* __restrict__ W2,
                                              __bf16* __restrict__ dst) {
  const int y = blockIdx.y;  // 0..2 -> W1 nets, 3..5 -> W2 nets
  const float* src = (y < 3) ? W1 + (size_t)(2 * y + 1) * 262144
                             : W2 + (size_t)(2 * (y - 3) + 1) * 262144;
  __bf16* d = dst + (size_t)y * 262144;
  const size_t i = ((size_t)blockIdx.x * 256 + threadIdx.x) * 4;
  f32x4 v = *(const f32x4*)&src[i];
  *(bf16x4*)&d[i] = __builtin_convertvector(v, bf16x4);
}

extern "C" void kernel_launch(void* const* d_in, const int* in_sizes, int n_in,
                              void* d_out, int out_size, void* d_ws, size_t ws_size,
                              hipStream_t stream) {
  const float* hx  = (const float*)d_in[0];
  // d_in[1] = cx1 (dead: cy1 is never returned)
  const float* cx2 = (const float*)d_in[2];
  const float* W1  = (const float*)d_in[3];
  const float* b1  = (const float*)d_in[4];
  const float* W2  = (const float*)d_in[5];
  const float* b2  = (const float*)d_in[6];
  float* out = (float*)d_out;

  // ws: W1b @0 (1.5MB) | W2b @1.5MB | a1 @3MB (48MB) | gates @51MB (32MB)
  char* ws = (char*)d_ws;
  __bf16* W1b   = (__bf16*)(ws);
  __bf16* W2b   = (__bf16*)(ws + 1572864);
  __bf16* a1    = (__bf16*)(ws + 3145728);
  __bf16* gates = (__bf16*)(ws + 53477376);

  cvt_w6<<<dim3(256, 6), 256, 0, stream>>>(W1, W2, W1b);

  // layer 1 (3 nets), hx fp32 read + converted in-kernel
  gemm_kernel<1><<<dim3(128, 4, 3), 256, 0, stream>>>(
      hx, nullptr, W1b, b1, a1, nullptr, nullptr, nullptr);
  // layer 2 gates i2, f2
  gemm_kernel<2><<<dim3(128, 4, 2), 256, 0, stream>>>(
      nullptr, a1, W2b, b2, gates, nullptr, nullptr, nullptr);
  // layer 2 z + final combine
  gemm_kernel<3><<<dim3(128, 4, 1), 256, 0, stream>>>(
      nullptr, a1, W2b, b2, nullptr, gates, cx2, out);
}

// Round 4
// 236.615 us; speedup vs baseline: 2.0156x; 1.1472x over previous
//
#include <hip/hip_runtime.h>
#include <hip/hip_bf16.h>

typedef __attribute__((ext_vector_type(8))) __bf16 bf16x8;
typedef __attribute__((ext_vector_type(4))) __bf16 bf16x4;
typedef __attribute__((ext_vector_type(4))) float f32x4;

constexpr int M = 16384;
constexpr int K = 512;
constexpr int BK = 32;

__device__ __forceinline__ void async_copy16(const void* gsrc, void* ldst) {
  __builtin_amdgcn_global_load_lds(
      (const __attribute__((address_space(1))) unsigned int*)(gsrc),
      (__attribute__((address_space(3))) unsigned int*)(ldst),
      16, 0, 0);
}

__device__ __forceinline__ float frcp(float x) { return __builtin_amdgcn_rcpf(x); }
__device__ __forceinline__ float ftanh(float x) {
  return 1.0f - 2.0f * frcp(1.0f + __expf(2.0f * x));
}
__device__ __forceinline__ float fsigm(float x) { return frcp(1.0f + __expf(-x)); }

// Epilogue scratch swizzle: row stride is 128 els (256B, bank-aligned), so
// conflict-freedom needs a per-row XOR on the 8-el chunk index. Key gives the
// 4 kc row-groups (rows rowq+r, rowq=4kc) 4 DISTINCT shifts mod 64 els
// -> stores spread over all 32 banks (2-way max = free, m136); reads cover
// each 256B row exactly once (uniform 1KB per wave-instr = minimal cycles).
__device__ __forceinline__ int kswz(int row) {
  return ((row & 3) << 3) ^ ((row & 12) << 2);
}

// ---------------------------------------------------------------------------
// R4: same proven skeleton (256 thr, 128x128 tile, BK=32, 4 waves 2x2, no
// spill), two targeted fixes from R3 counters:
//  - MODE 1 (a1 = tanh(hx@W1^T+b1), hx fp32): A-staging is now load-EARLY /
//    ds_write-LATE. R3 issued the ds_write before the MFMA phase, so every
//    K-step stalled on vmcnt for the hx loads before any MFMA. Now: loads
//    issued right after the barrier (oldest vmem -> vmcnt(2) keeps W async
//    copies in flight), MFMA phase runs, THEN the converted tile is written
//    to the next LDS buffer (published by the next barrier).
//  - MODE 3 (z + combine): R3 did per-lane scattered epilogue (2B/4B at
//    col=ni*16+fr -> 32B segments, 4.5% Mfma, 16% HBM, 68us). Now z goes
//    through the LDS scratch like MODE 1/2 and the combine runs as a
//    coalesced it-loop (16B gate loads, 32B cx2 loads, 32B stores).
//  - scratch restride 136->128 (+kswz) -> LDS 34->32 KB -> 5 blocks/CU cap.
// R1/R2 POST-MORTEM kept: megafusion (1 block/CU) dead-ends in spill + zero
// TLP. NOTE: never partially-unroll loops indexing acc[] (scratch spill).
// ---------------------------------------------------------------------------
template <int MODE>
__global__ __launch_bounds__(256) void gemm_kernel(
    const float* __restrict__ hx,      // MODE1 A source [M][512] fp32
    const __bf16* __restrict__ Ab,     // MODE2/3 A source planes [3][M][512]
    const __bf16* __restrict__ W,      // [3][512][512] bf16 (N,K) row-major
    const float* __restrict__ bias,    // [7][512] fp32
    __bf16* __restrict__ outb,         // MODE1: a1 base; MODE2: gates base
    const __bf16* __restrict__ gates,  // MODE3: [2][M][512] bf16 (i2, f2)
    const float* __restrict__ cx2,     // MODE3
    float* __restrict__ outf)          // MODE3: [M][512] fp32
{
  const int j = blockIdx.z;
  const int jj = (MODE == 3) ? 2 : j;         // net index
  const int mbase = blockIdx.x * 128;
  const int nbase = blockIdx.y * 128;
  constexpr size_t NH = (size_t)M * 512;

  const __bf16* Wj = W + (size_t)jj * 262144;
  const __bf16* Abj = (MODE >= 2) ? Ab + (size_t)jj * NH : nullptr;
  const int brow = 2 * jj + 1;                // i2=1, f2=3, z=5

  // dbuf: 2 x (As 4096 el + Bs 4096 el) = 16384 el = 32 KB.
  // epilogue scratch reuses the same 16384 el ([128][128], kswz'd).
  __shared__ __align__(16) __bf16 smem[16384];

  const int tid  = threadIdx.x;
  const int wid  = tid >> 6;
  const int lane = tid & 63;
  const int wm   = (wid >> 1) * 64;
  const int wn   = (wid & 1) * 64;
  const int srow = wid * 16 + (lane >> 2);
  const int scol = ((lane & 3) ^ ((lane >> 3) & 3)) * 8;  // swizzled src chunk
  const int fr   = lane & 15;
  const int kc   = lane >> 4;
  const int sw   = (fr >> 1) & 3;
  const int rowq = kc * 4;

  // MODE1 A reg-staging: 2 threads/row, each covers 2 chunks (16 floats).
  const int ar = tid >> 1;              // row 0..127
  const int cb = (tid & 1) * 2;         // first of 2 chunks (chunk = 8 els)
  const int asw = (ar >> 1) & 3;        // same row-swizzle as frag reads
  const float* hxrow =
      (MODE == 1) ? hx + (size_t)(mbase + ar) * K + cb * 8 : nullptr;

  auto stageW = [&](int p, int k0) {
    __bf16* As = smem + p * 8192;
    __bf16* Bs = As + 4096;
#pragma unroll
    for (int r = 0; r < 2; ++r)
      async_copy16(Wj + (size_t)(nbase + r * 64 + srow) * K + (k0 + scol),
                   (void*)&Bs[(r * 64 + wid * 16) * BK]);
    if constexpr (MODE >= 2) {
#pragma unroll
      for (int r = 0; r < 2; ++r)
        async_copy16(Abj + (size_t)(mbase + r * 64 + srow) * K + (k0 + scol),
                     (void*)&As[(r * 64 + wid * 16) * BK]);
    }
  };

  // MODE1 A tile in flight (named regs, no dynamic indexing)
  f32x4 av0, av1, av2, av3;
  auto loadA = [&](int k0) {
    const float* hp = hxrow + k0;
    av0 = *(const f32x4*)(hp);
    av1 = *(const f32x4*)(hp + 4);
    av2 = *(const f32x4*)(hp + 8);
    av3 = *(const f32x4*)(hp + 12);
  };
  auto writeA = [&](int p) {
    __bf16* As_ = smem + p * 8192 + ar * 32;
    *(bf16x4*)&As_[(cb ^ asw) * 8]           = __builtin_convertvector(av0, bf16x4);
    *(bf16x4*)&As_[(cb ^ asw) * 8 + 4]       = __builtin_convertvector(av1, bf16x4);
    *(bf16x4*)&As_[((cb + 1) ^ asw) * 8]     = __builtin_convertvector(av2, bf16x4);
    *(bf16x4*)&As_[((cb + 1) ^ asw) * 8 + 4] = __builtin_convertvector(av3, bf16x4);
  };

  f32x4 acc[4][4] = {};

  if constexpr (MODE == 1) {
    loadA(0);        // oldest vmem
    stageW(0, 0);
    writeA(0);       // one-time vmcnt stall in prologue only
  } else {
    stageW(0, 0);
  }

  int p = 0;
  for (int k0 = 0; k0 < K; k0 += BK) {
    __syncthreads();  // publishes buffer p (W async + A ds_write of last iter)
    const bool pre = k0 + BK < K;
    if (pre) {
      if constexpr (MODE == 1) loadA(k0 + BK);  // oldest -> hides under MFMA
      stageW(p ^ 1, k0 + BK);
    }

    const __bf16* As = smem + p * 8192;
    const __bf16* Bs = As + 4096;
    bf16x8 af[4], bfr[4];
#pragma unroll
    for (int i = 0; i < 4; ++i) {
      af[i]  = *(const bf16x8*)&As[(wm + i * 16 + fr) * BK + ((kc ^ sw) * 8)];
      bfr[i] = *(const bf16x8*)&Bs[(wn + i * 16 + fr) * BK + ((kc ^ sw) * 8)];
    }
#pragma unroll
    for (int mi = 0; mi < 4; ++mi)
#pragma unroll
      for (int ni = 0; ni < 4; ++ni)
        acc[mi][ni] = __builtin_amdgcn_mfma_f32_16x16x32_bf16(
            af[mi], bfr[ni], acc[mi][ni], 0, 0, 0);

    if constexpr (MODE == 1)
      if (pre) writeA(p ^ 1);  // safe: barrier above retired all p^1 reads
    p ^= 1;
  }

  // Epilogue. C/D layout: col=fr, row=rowq+r.
  float bv[4];
  const float* bj = bias + (size_t)brow * 512 + nbase + wn;
#pragma unroll
  for (int ni = 0; ni < 4; ++ni) bv[ni] = bj[ni * 16 + fr];

  __syncthreads();  // all frag reads done; smem reusable as C scratch
#pragma unroll
  for (int mi = 0; mi < 4; ++mi)
#pragma unroll
    for (int ni = 0; ni < 4; ++ni)
#pragma unroll
      for (int r = 0; r < 4; ++r) {
        float v = acc[mi][ni][r] + bv[ni];
        float res;
        if constexpr (MODE == 1) res = ftanh(v);
        else if constexpr (MODE == 2) res = fsigm(ftanh(v));
        else res = ftanh(fsigm(ftanh(v)));          // z (bf16-rounded below)
        const int row = wm + mi * 16 + rowq + r;
        const int col = wn + ni * 16 + fr;
        smem[row * 128 + (col ^ kswz(row))] = (__bf16)res;
      }
  __syncthreads();

  if constexpr (MODE <= 2) {
#pragma unroll
    for (int it = 0; it < 8; ++it) {
      const int s = it * 256 + tid;   // 0..2047
      const int row = s >> 4, ch = s & 15;
      bf16x8 v = *(const bf16x8*)&smem[row * 128 + ((ch * 8) ^ kswz(row))];
      *(bf16x8*)&outb[(size_t)j * NH + (size_t)(mbase + row) * 512 +
                      (nbase + ch * 8)] = v;
    }
  } else {
    // coalesced combine: out = f2*cx2 + i2*z (i2/f2 from prior dispatch,
    // stream-ordered; 16B/32B contiguous per lane)
#pragma unroll
    for (int it = 0; it < 8; ++it) {
      const int s = it * 256 + tid;
      const int row = s >> 4, ch = s & 15;
      const size_t gidx = (size_t)(mbase + row) * 512 + (nbase + ch * 8);
      bf16x8 zv = *(const bf16x8*)&smem[row * 128 + ((ch * 8) ^ kswz(row))];
      bf16x8 i2 = *(const bf16x8*)&gates[gidx];
      bf16x8 f2 = *(const bf16x8*)&gates[NH + gidx];
      f32x4 c0 = *(const f32x4*)&cx2[gidx];
      f32x4 c1 = *(const f32x4*)&cx2[gidx + 4];
      f32x4 r0, r1;
#pragma unroll
      for (int q = 0; q < 4; ++q) {
        r0[q] = (float)f2[q] * c0[q] + (float)i2[q] * (float)zv[q];
        r1[q] = (float)f2[4 + q] * c1[q] + (float)i2[4 + q] * (float)zv[4 + q];
      }
      *(f32x4*)&outf[gidx] = r0;
      *(f32x4*)&outf[gidx + 4] = r1;
    }
  }
}

// pick rows 2y+1 of W1/W2 ([7][512][512] fp32) -> [3][512][512] bf16 each
__global__ __launch_bounds__(256) void cvt_w6(const float* __restrict__ W1,
                                              const float* __restrict__ W2,
                                              __bf16* __restrict__ dst) {
  const int y = blockIdx.y;  // 0..2 -> W1 nets, 3..5 -> W2 nets
  const float* src = (y < 3) ? W1 + (size_t)(2 * y + 1) * 262144
                             : W2 + (size_t)(2 * (y - 3) + 1) * 262144;
  __bf16* d = dst + (size_t)y * 262144;
  const size_t i = ((size_t)blockIdx.x * 256 + threadIdx.x) * 4;
  f32x4 v = *(const f32x4*)&src[i];
  *(bf16x4*)&d[i] = __builtin_convertvector(v, bf16x4);
}

extern "C" void kernel_launch(void* const* d_in, const int* in_sizes, int n_in,
                              void* d_out, int out_size, void* d_ws, size_t ws_size,
                              hipStream_t stream) {
  const float* hx  = (const float*)d_in[0];
  // d_in[1] = cx1 (dead: cy1 is never returned)
  const float* cx2 = (const float*)d_in[2];
  const float* W1  = (const float*)d_in[3];
  const float* b1  = (const float*)d_in[4];
  const float* W2  = (const float*)d_in[5];
  const float* b2  = (const float*)d_in[6];
  float* out = (float*)d_out;

  // ws: W1b @0 (1.5MB) | W2b @1.5MB | a1 @3MB (48MB) | gates @51MB (32MB)
  char* ws = (char*)d_ws;
  __bf16* W1b   = (__bf16*)(ws);
  __bf16* W2b   = (__bf16*)(ws + 1572864);
  __bf16* a1    = (__bf16*)(ws + 3145728);
  __bf16* gates = (__bf16*)(ws + 53477376);

  cvt_w6<<<dim3(256, 6), 256, 0, stream>>>(W1, W2, W1b);

  // layer 1 (3 nets), hx fp32 read + converted in-kernel
  gemm_kernel<1><<<dim3(128, 4, 3), 256, 0, stream>>>(
      hx, nullptr, W1b, b1, a1, nullptr, nullptr, nullptr);
  // layer 2 gates i2, f2
  gemm_kernel<2><<<dim3(128, 4, 2), 256, 0, stream>>>(
      nullptr, a1, W2b, b2, gates, nullptr, nullptr, nullptr);
  // layer 2 z + final combine
  gemm_kernel<3><<<dim3(128, 4, 1), 256, 0, stream>>>(
      nullptr, a1, W2b, b2, nullptr, gates, cx2, out);
}

// Round 6
// 224.144 us; speedup vs baseline: 2.1278x; 1.0556x over previous
//
#include <hip/hip_runtime.h>
#include <hip/hip_bf16.h>

typedef __attribute__((ext_vector_type(8))) __bf16 bf16x8;
typedef __attribute__((ext_vector_type(4))) __bf16 bf16x4;
typedef __attribute__((ext_vector_type(4))) float f32x4;

constexpr int M = 16384;
constexpr int K = 512;
constexpr int BK = 32;
constexpr int NT = 16;       // K / BK

__device__ __forceinline__ void async_copy16(const void* gsrc, void* ldst) {
  __builtin_amdgcn_global_load_lds(
      (const __attribute__((address_space(1))) unsigned int*)(gsrc),
      (__attribute__((address_space(3))) unsigned int*)(ldst),
      16, 0, 0);
}

__device__ __forceinline__ float frcp(float x) { return __builtin_amdgcn_rcpf(x); }
__device__ __forceinline__ float ftanh(float x) {
  return 1.0f - 2.0f * frcp(1.0f + __expf(2.0f * x));
}
__device__ __forceinline__ float fsigm(float x) { return frcp(1.0f + __expf(-x)); }

// Epilogue scratch swizzle (R4-proven): row stride 128 els (256B, bank-
// aligned); per-row XOR on the 8-el chunk gives the 4 kc row-groups distinct
// shifts -> stores 2-way max (free), reads cover each row once.
__device__ __forceinline__ int kswz(int row) {
  return ((row & 3) << 3) ^ ((row & 12) << 2);
}

// ---------------------------------------------------------------------------
// R6 = R5 with the barrier race FIXED (guide rule #18 class).
// R5 POST-MORTEM: raw s_barrier + separate vmcnt asm let hipcc sink the
// lgkmcnt-wait+MFMA cluster PAST the barrier ("memory" clobber doesn't order
// register-only ops). A wave could cross barrier u with its ds_reads of
// buffer (u+2)%3 still in flight while another wave's stage() DMA overwrote
// that buffer (3-buffer rotation re-writes one barrier after last read)
// -> intermittent tile corruption, absmax 0.24. FIX:
//   s_waitcnt vmcnt(N) lgkmcnt(0)   (ONE asm: wave's ds_reads provably done
//                                    pre-barrier; memory clobber pins them)
//   s_barrier
//   sched_barrier(0)                (nothing below schedules above)
// Counted-vmcnt benefit preserved: tile t+2's 4 copies stay in flight across
// the barrier (never drain to 0 mid-loop; AITER/T4 pattern).
// Pipeline: 3 buffers, stage K-tile t+2 while computing t; lookahead 2
// K-steps (~700-800cy) ~ HBM/L3 latency.
// MODES: 1: a1=tanh(hx@W1^T+b1) all 3 nets; 2: gates=sigm(tanh(a1@W2^T+b2))
// j in {0,1}; 3: z-net + combine out = f2*cx2 + i2*z (gates from prior
// dispatch, stream-ordered; coalesced via LDS scratch - R4-proven).
// LDS: 3 x (As 4096 + Bs 4096) el = 48KB -> 3 blocks/CU cap.
// NOTE: never runtime-index acc[]/frag arrays (scratch spill lesson).
// ---------------------------------------------------------------------------
template <int MODE>
__global__ __launch_bounds__(256) void gemm_kernel(
    const __bf16* __restrict__ Ab,     // MODE1: hxb [M][512]; else a1 planes
    const __bf16* __restrict__ W,      // [3][512][512] bf16 (N,K) row-major
    const float* __restrict__ bias,    // [7][512] fp32
    __bf16* __restrict__ outb,         // MODE1: a1 base; MODE2: gates base
    const __bf16* __restrict__ gates,  // MODE3: [2][M][512] bf16 (i2, f2)
    const float* __restrict__ cx2,     // MODE3
    float* __restrict__ outf)          // MODE3: [M][512] fp32
{
  const int j = blockIdx.z;
  const int jj = (MODE == 3) ? 2 : j;         // net index
  const int mbase = blockIdx.x * 128;
  const int nbase = blockIdx.y * 128;
  constexpr size_t NH = (size_t)M * 512;

  const __bf16* Aj = (MODE == 1) ? Ab : Ab + (size_t)jj * NH;
  const __bf16* Wj = W + (size_t)jj * 262144;
  const int brow = 2 * jj + 1;                // b-row: i2=1, f2=3, z=5

  // 3 staging buffers x 8192 el (16KB each) = 48KB; scratch reuses [0..16383]
  __shared__ __align__(16) __bf16 smem[24576];

  const int tid  = threadIdx.x;
  const int wid  = tid >> 6;
  const int lane = tid & 63;
  const int wm   = (wid >> 1) * 64;
  const int wn   = (wid & 1) * 64;
  const int srow = wid * 16 + (lane >> 2);
  const int scol = ((lane & 3) ^ ((lane >> 3) & 3)) * 8;  // swizzled src chunk
  const int fr   = lane & 15;
  const int kc   = lane >> 4;
  const int sw   = (fr >> 1) & 3;
  const int rowq = kc * 4;

  auto stage = [&](int p, int k0) {
    __bf16* As = smem + p * 8192;
    __bf16* Bs = As + 4096;
#pragma unroll
    for (int r = 0; r < 2; ++r) {
      async_copy16(Aj + (size_t)(mbase + r * 64 + srow) * K + (k0 + scol),
                   (void*)&As[(r * 64 + wid * 16) * BK]);
      async_copy16(Wj + (size_t)(nbase + r * 64 + srow) * K + (k0 + scol),
                   (void*)&Bs[(r * 64 + wid * 16) * BK]);
    }
  };

  f32x4 acc[4][4] = {};

  stage(0, 0);
  stage(1, BK);
  int pr = 0, ps = 2;
  for (int t = 0; t < NT; ++t) {
    // ONE waitcnt: retire this wave's ds_reads (lgkmcnt 0) AND everything
    // but the newest stage (vmcnt 4) BEFORE the barrier. Tile t+2's copies
    // stay in flight across it (never drain to 0 mid-loop).
    if (t < NT - 2) asm volatile("s_waitcnt vmcnt(4) lgkmcnt(0)" ::: "memory");
    else            asm volatile("s_waitcnt vmcnt(0) lgkmcnt(0)" ::: "memory");
    __builtin_amdgcn_s_barrier();
    __builtin_amdgcn_sched_barrier(0);   // rule #18: pin code below the bar
    if (t < NT - 2) stage(ps, (t + 2) * BK);

    const __bf16* As = smem + pr * 8192;
    const __bf16* Bs = As + 4096;
    bf16x8 af[4], bfr[4];
#pragma unroll
    for (int i = 0; i < 4; ++i) {
      af[i]  = *(const bf16x8*)&As[(wm + i * 16 + fr) * BK + ((kc ^ sw) * 8)];
      bfr[i] = *(const bf16x8*)&Bs[(wn + i * 16 + fr) * BK + ((kc ^ sw) * 8)];
    }
#pragma unroll
    for (int mi = 0; mi < 4; ++mi)
#pragma unroll
      for (int ni = 0; ni < 4; ++ni)
        acc[mi][ni] = __builtin_amdgcn_mfma_f32_16x16x32_bf16(
            af[mi], bfr[ni], acc[mi][ni], 0, 0, 0);

    pr = (pr == 2) ? 0 : pr + 1;
    ps = (ps == 2) ? 0 : ps + 1;
  }

  // Epilogue. C/D layout: col=fr, row=rowq+r.
  float bv[4];
  const float* bj = bias + (size_t)brow * 512 + nbase + wn;
#pragma unroll
  for (int ni = 0; ni < 4; ++ni) bv[ni] = bj[ni * 16 + fr];

  __syncthreads();  // full drain once; smem reusable as C scratch
#pragma unroll
  for (int mi = 0; mi < 4; ++mi)
#pragma unroll
    for (int ni = 0; ni < 4; ++ni)
#pragma unroll
      for (int r = 0; r < 4; ++r) {
        float v = acc[mi][ni][r] + bv[ni];
        float res;
        if constexpr (MODE == 1) res = ftanh(v);
        else if constexpr (MODE == 2) res = fsigm(ftanh(v));
        else res = ftanh(fsigm(ftanh(v)));          // z (bf16-rounded below)
        const int row = wm + mi * 16 + rowq + r;
        const int col = wn + ni * 16 + fr;
        smem[row * 128 + (col ^ kswz(row))] = (__bf16)res;
      }
  __syncthreads();

  if constexpr (MODE <= 2) {
#pragma unroll
    for (int it = 0; it < 8; ++it) {
      const int s = it * 256 + tid;   // 0..2047
      const int row = s >> 4, ch = s & 15;
      bf16x8 v = *(const bf16x8*)&smem[row * 128 + ((ch * 8) ^ kswz(row))];
      *(bf16x8*)&outb[(size_t)j * NH + (size_t)(mbase + row) * 512 +
                      (nbase + ch * 8)] = v;
    }
  } else {
    // coalesced combine: out = f2*cx2 + i2*z (16B/32B contiguous per lane)
#pragma unroll
    for (int it = 0; it < 8; ++it) {
      const int s = it * 256 + tid;
      const int row = s >> 4, ch = s & 15;
      const size_t gidx = (size_t)(mbase + row) * 512 + (nbase + ch * 8);
      bf16x8 zv = *(const bf16x8*)&smem[row * 128 + ((ch * 8) ^ kswz(row))];
      bf16x8 i2 = *(const bf16x8*)&gates[gidx];
      bf16x8 f2 = *(const bf16x8*)&gates[NH + gidx];
      f32x4 c0 = *(const f32x4*)&cx2[gidx];
      f32x4 c1 = *(const f32x4*)&cx2[gidx + 4];
      f32x4 r0, r1;
#pragma unroll
      for (int q = 0; q < 4; ++q) {
        r0[q] = (float)f2[q] * c0[q] + (float)i2[q] * (float)zv[q];
        r1[q] = (float)f2[4 + q] * c1[q] + (float)i2[4 + q] * (float)zv[4 + q];
      }
      *(f32x4*)&outf[gidx] = r0;
      *(f32x4*)&outf[gidx + 4] = r1;
    }
  }
}

// One conversion dispatch: blocks [0,1536) pick rows 2y+1 of W1/W2
// ([7][512][512] fp32) -> Wb [6][512][512] bf16; blocks [1536,9728) convert
// hx [M][512] fp32 -> hxb bf16.
__global__ __launch_bounds__(256) void cvt_all(const float* __restrict__ hx,
                                               const float* __restrict__ W1,
                                               const float* __restrict__ W2,
                                               __bf16* __restrict__ hxb,
                                               __bf16* __restrict__ Wb) {
  const int b = blockIdx.x;
  if (b < 1536) {
    const int y = b >> 8;          // 0..5
    const int bb = b & 255;
    const float* src = (y < 3) ? W1 + (size_t)(2 * y + 1) * 262144
                               : W2 + (size_t)(2 * (y - 3) + 1) * 262144;
    __bf16* d = Wb + (size_t)y * 262144;
    const size_t i = ((size_t)bb * 256 + threadIdx.x) * 4;
    f32x4 v = *(const f32x4*)&src[i];
    *(bf16x4*)&d[i] = __builtin_convertvector(v, bf16x4);
  } else {
    const size_t i = ((size_t)(b - 1536) * 256 + threadIdx.x) * 4;
    f32x4 v = *(const f32x4*)&hx[i];
    *(bf16x4*)&hxb[i] = __builtin_convertvector(v, bf16x4);
  }
}

extern "C" void kernel_launch(void* const* d_in, const int* in_sizes, int n_in,
                              void* d_out, int out_size, void* d_ws, size_t ws_size,
                              hipStream_t stream) {
  const float* hx  = (const float*)d_in[0];
  // d_in[1] = cx1 (dead: cy1 is never returned)
  const float* cx2 = (const float*)d_in[2];
  const float* W1  = (const float*)d_in[3];
  const float* b1  = (const float*)d_in[4];
  const float* W2  = (const float*)d_in[5];
  const float* b2  = (const float*)d_in[6];
  float* out = (float*)d_out;

  // ws: Wb @0 (3MB, [6] planes: 0-2=W1, 3-5=W2) | hxb @3MB (16MB) |
  //     a1 @19922944 (48MB) | gates @70254592 (32MB) -> ~102MB
  char* ws = (char*)d_ws;
  __bf16* Wb    = (__bf16*)(ws);
  __bf16* hxb   = (__bf16*)(ws + 3145728);
  __bf16* a1    = (__bf16*)(ws + 19922944);
  __bf16* gates = (__bf16*)(ws + 70254592);
  __bf16* W2b   = Wb + 3 * 262144;

  cvt_all<<<9728, 256, 0, stream>>>(hx, W1, W2, hxb, Wb);

  // layer 1 (3 nets)
  gemm_kernel<1><<<dim3(128, 4, 3), 256, 0, stream>>>(
      hxb, Wb, b1, a1, nullptr, nullptr, nullptr);
  // layer 2 gates i2, f2
  gemm_kernel<2><<<dim3(128, 4, 2), 256, 0, stream>>>(
      a1, W2b, b2, gates, nullptr, nullptr, nullptr);
  // layer 2 z + final combine
  gemm_kernel<3><<<dim3(128, 4, 1), 256, 0, stream>>>(
      a1, W2b, b2, nullptr, gates, cx2, out);
}